// Round 18
// baseline (147.225 us; speedup 1.0000x reference)
//
#include <hip/hip_runtime.h>

// CTC loss forward (sum), faithful to the JAX reference.
// T=2048, N=256, C=128, L=200, S=2L+1=401.
//
// r17 skeleton (best, 143us): one workgroup (4 waves) per sample, LOG2
// domain, wave w owns states 128w..128w+127, 2/lane (s0=2idx blank,
// s1=2idx+1 label). Intra-wave halo via DPP wave_shr:1 (old operand injects
// the cross-wave boundary). Cross-wave left->right only, 16-step blocks,
// monotonic per-wave flags, double-buffered boundary prefetch, batched
// lane-63 boundary bursts, fenced inline-asm label-score double buffer.
//
// Round-18 delta: BLANK TIMELINE IN LDS. pred[t][n][0] is wave-uniform and
// shared by all 4 waves; r17 loaded it 4x2048 times through the fenced VMEM
// path. Now one cooperative 8KB burst stages the whole blank timeline into
// LDS at start (shifted by -1 so block reads are 16B-aligned); each block
// reads its 16 blanks via 4x ds_read_b128 broadcast, double-buffered one
// block ahead (latency hidden). Halves VMEM issue (16 loads/block,
// vmcnt(16)), halves fenced-register demand, drops the vB opaque reg.

#define TT 2048
#define NN 256
#define CC 128
#define LL 200

#define K_LOG2E 1.4426950408889634f
#define K_LN2   0.6931471805599453f
#define NEGB   (-1.44e30f)   /* -1e30 * log2(e) */
#define PEN    (-2.0e30f)    /* 'disallowed' halo for wave 0 */
#define NC4    131072u       /* NN*CC*4 bytes: stride between time rows */

__device__ __forceinline__ float max3f(float a, float b, float c) {
    float r; asm("v_max3_f32 %0, %1, %2, %3" : "=v"(r) : "v"(a), "v"(b), "v"(c)); return r;
}

__global__ __launch_bounds__(256, 1)
void ctc_alpha(const float* __restrict__ pred,
               const int* __restrict__ target,
               const int* __restrict__ tlen,
               float* __restrict__ loss_ws)
{
    // [w][b][k]: boundary state 128w+127 AFTER step 16b+1+k; row 4 = PEN.
    __shared__ float blk[5][128][16];
    __shared__ float scb_lds[TT];  // scb_lds[t-1] = pred[t][n][0], t=1..2047
    __shared__ int   flags[8];     // [w]=blocks completed; [7]=INT_MAX dummy

    const int tid  = threadIdx.x;
    const int wid  = tid >> 6;
    const int lane = tid & 63;
    const int n    = blockIdx.x;

    if (tid < 8) flags[tid] = (tid >= 4) ? 0x7fffffff : 0;
    for (int i = tid; i < 128 * 16; i += 256) ((float*)blk[4])[i] = PEN;
    // blank timeline: one cooperative burst (2047 scattered dword loads)
    for (int i = tid; i < TT - 1; i += 256)
        scb_lds[i] = pred[(size_t)(i + 1) * (NN * CC) + n * CC];
    if (tid == 0) scb_lds[TT - 1] = 0.0f;   // never consumed; keep finite

    // per-state constants. Reference quirk: starts[0]=0, starts[n>0]=tlen[n-1].
    const int start = (n == 0) ? 0 : tlen[n - 1];
    const int idx   = (wid << 6) | lane;     // s0 = 2*idx (blank), s1 = 2*idx+1
    int lab1 = 0; float msk1 = 0.0f;
    if (idx < LL) {
        lab1 = target[start + idx];
        if (idx >= 1 && lab1 != target[start + idx - 1]) msk1 = 1.0f;
    }

    // ---- alpha_0 (log2 domain): only states 0,1 (idx==0) live ----
    float al0, al1;
    {
        const float eB = pred[n * CC];
        const float eL = pred[n * CC + lab1];
        al0 = (idx == 0) ? K_LOG2E * eB : NEGB;
        al1 = (idx == 0) ? K_LOG2E * eL : NEGB;
    }
    __syncthreads();   // flags + PEN row + scb_lds visible before any spin

    // ---- label-score double buffer: per-lane byte offset + uniform row ptr ----
    const char* rp = (const char*)pred + (size_t)(NN * CC + n * CC) * 4u;  // row 1
    uint32_t vL = (uint32_t)lab1 * 4u;        // label class byte-offset
    asm volatile("" : "+v"(vL));              // pin to a VGPR

    float sAL[16], sBL[16];                   // two 16-reg label-score sets

    // 16 hand-issued loads for the 16 rows starting at rp (advances rp).
#define PREF_SC(PL)                                                            \
    {                                                                          \
        _Pragma("unroll")                                                      \
        for (int j = 0; j < 16; ++j) {                                         \
            asm volatile("global_load_dword %0, %1, %2"                        \
                : "=&v"(PL[j]) : "v"(vL), "s"(rp) : "memory");                 \
            rp += NC4;                                                         \
        }                                                                      \
    }
    // Clamped variant for the last prefetch (row 2048 doesn't exist: dup 2047).
#define PREF_SC_CLAMP(PL)                                                      \
    {                                                                          \
        _Pragma("unroll")                                                      \
        for (int j = 0; j < 15; ++j) {                                         \
            asm volatile("global_load_dword %0, %1, %2"                        \
                : "=&v"(PL[j]) : "v"(vL), "s"(rp) : "memory");                 \
            rp += NC4;                                                         \
        }                                                                      \
        const char* rp2 = rp - NC4;                                            \
        asm volatile("global_load_dword %0, %1, %2"                            \
            : "=&v"(PL[15]) : "v"(vL), "s"(rp2) : "memory");                   \
    }

    // Zero-cost dataflow fence: redefine all 16 regs at this program point.
#define KA(S)                                                                  \
    asm volatile("" : "+v"(S[0]), "+v"(S[1]), "+v"(S[2]),  "+v"(S[3]),         \
                      "+v"(S[4]), "+v"(S[5]), "+v"(S[6]),  "+v"(S[7]));        \
    asm volatile("" : "+v"(S[8]), "+v"(S[9]), "+v"(S[10]), "+v"(S[11]),        \
                      "+v"(S[12]),"+v"(S[13]),"+v"(S[14]), "+v"(S[15]));

    asm volatile("s_waitcnt vmcnt(0)" ::: "memory");   // exact vmcnt bookkeeping
    PREF_SC(sAL)                                       // rows 1..16 -> set A

    float (* const blkC)[16] = blk[(wid == 0) ? 4 : (wid - 1)];
    float (* const blkW)[16] = blk[wid];
    volatile int* pflag = &flags[(wid == 0) ? 7 : (wid - 1)];
    volatile int* mflag = &flags[wid];
    int fval = *pflag;

    float bndA[16], bndB[16], bw[16];
    float scbA[16], scbB[16];
    float bprev = (wid == 0) ? PEN : NEGB;    // boundary after step 0 (alpha0)

#define UNPACK16(DST, q)                                                       \
    {                                                                          \
        const float4 v0 = q[0], v1 = q[1], v2 = q[2], v3 = q[3];               \
        DST[0]=v0.x;  DST[1]=v0.y;  DST[2]=v0.z;  DST[3]=v0.w;                 \
        DST[4]=v1.x;  DST[5]=v1.y;  DST[6]=v1.z;  DST[7]=v1.w;                 \
        DST[8]=v2.x;  DST[9]=v2.y;  DST[10]=v2.z; DST[11]=v2.w;                \
        DST[12]=v3.x; DST[13]=v3.y; DST[14]=v3.z; DST[15]=v3.w;                \
    }
#define LOAD_BLK(DST, B)                                                       \
    { const float4* q = (const float4*)&blkC[B][0];    UNPACK16(DST, q) }
#define LOAD_SCB(DST, B)                                                       \
    { const float4* q = (const float4*)&scb_lds[16*(B)]; UNPACK16(DST, q) }

#define STORE_BLK(B)                                                           \
    if (lane == 63) {                                                          \
        float4* d = (float4*)&blkW[B][0];                                      \
        d[0] = make_float4(bw[0],  bw[1],  bw[2],  bw[3]);                     \
        d[1] = make_float4(bw[4],  bw[5],  bw[6],  bw[7]);                     \
        d[2] = make_float4(bw[8],  bw[9],  bw[10], bw[11]);                    \
        d[3] = make_float4(bw[12], bw[13], bw[14], bw[15]);                    \
    }

    // One step, PH = 0..15 (no loads inside). Halo h1 = prev lane's al1;
    // lane0 <- boundary via update_dpp old operand (wave_shr:1 = 0x138).
#define CTC_STEP(PH, BV, USC, UL)                                              \
    {                                                                          \
        const float hold = ((PH) == 0) ? bprev : BV[((PH) + 15) & 15];         \
        const int h1i = __builtin_amdgcn_update_dpp(                           \
            __float_as_int(hold), __float_as_int(al1), 0x138, 0xf, 0xf, false);\
        const float h1 = __int_as_float(h1i);                                  \
        const float M  = max3f(al1, al0, h1);                                  \
        const float b1 = fmaf(K_LOG2E, UL[PH], M);                             \
        const float b0 = fmaf(K_LOG2E, USC[PH], M);                            \
        const float e1 = __builtin_amdgcn_exp2f(al1 - M);                      \
        const float e0 = __builtin_amdgcn_exp2f(al0 - M);                      \
        const float eh = __builtin_amdgcn_exp2f(h1 - M);                       \
        const float s1 = fmaf(eh, msk1, e1 + e0);                              \
        const float s0 = e0 + eh;                                              \
        al1 = b1 + __builtin_amdgcn_logf(s1);                                  \
        al0 = b0 + __builtin_amdgcn_logf(s0);                                  \
        bw[PH] = al1;                                                          \
    }

    // Block B: consume label set UL / blank set USC / boundaries BUSE;
    // prefetch label set PL (asm), blank set PSC + boundaries BPRE (LDS).
#define RUN_BLOCK(B, UL, PL, USC, PSC, BUSE, BPRE, NEED, CLAMP)                \
    {                                                                          \
        if (CLAMP) { PREF_SC_CLAMP(PL) } else { PREF_SC(PL) }                  \
        const int need_ = (NEED);                                              \
        if (fval < need_) { do { fval = *pflag; } while (fval < need_); }      \
        asm volatile("" ::: "memory");                                         \
        LOAD_BLK(BPRE, (B) + 1)                                                \
        LOAD_SCB(PSC, (B) + 1)                                                 \
        asm volatile("s_waitcnt vmcnt(16)" ::: "memory");  /* set UL landed */ \
        __builtin_amdgcn_sched_barrier(0);                                     \
        KA(UL)                               /* dataflow fence on set UL */    \
        CTC_STEP( 0, BUSE, USC, UL) CTC_STEP( 1, BUSE, USC, UL)                \
        CTC_STEP( 2, BUSE, USC, UL) CTC_STEP( 3, BUSE, USC, UL)                \
        CTC_STEP( 4, BUSE, USC, UL) CTC_STEP( 5, BUSE, USC, UL)                \
        CTC_STEP( 6, BUSE, USC, UL) CTC_STEP( 7, BUSE, USC, UL)                \
        CTC_STEP( 8, BUSE, USC, UL) CTC_STEP( 9, BUSE, USC, UL)                \
        CTC_STEP(10, BUSE, USC, UL) CTC_STEP(11, BUSE, USC, UL)                \
        CTC_STEP(12, BUSE, USC, UL) CTC_STEP(13, BUSE, USC, UL)                \
        CTC_STEP(14, BUSE, USC, UL) CTC_STEP(15, BUSE, USC, UL)                \
        STORE_BLK(B)                                                           \
        asm volatile("" ::: "memory");       /* burst before flag post */      \
        if (lane == 0) *mflag = (B) + 1;                                       \
        bprev = BUSE[15];                                                      \
        fval = *pflag;                                                         \
    }

    // prologue: block 0's boundaries + blank set 0
    if (fval < 1) { do { fval = *pflag; } while (fval < 1); }
    asm volatile("" ::: "memory");
    LOAD_BLK(bndA, 0)
    LOAD_SCB(scbA, 0)

    // main: blocks 0..125 (t = 1..2016), ping-pong all buffers
    for (int bb = 0; bb < 63; ++bb) {
        RUN_BLOCK(2 * bb,     sAL, sBL, scbA, scbB, bndA, bndB, 2 * bb + 2, 0)
        RUN_BLOCK(2 * bb + 1, sBL, sAL, scbB, scbA, bndB, bndA, 2 * bb + 3, 0)
    }

    // block 126 (t=2017..2032): prefetch rows 2033..2047 (clamped) + block 127
    RUN_BLOCK(126, sAL, sBL, scbA, scbB, bndA, bndB, 128, 1)

    // tail block 127: t = 2033..2047 (15 steps), sets B already resident.
    {
        asm volatile("s_waitcnt vmcnt(0)" ::: "memory");
        __builtin_amdgcn_sched_barrier(0);
        KA(sBL)
        CTC_STEP( 0, bndB, scbB, sBL) CTC_STEP( 1, bndB, scbB, sBL)
        CTC_STEP( 2, bndB, scbB, sBL) CTC_STEP( 3, bndB, scbB, sBL)
        CTC_STEP( 4, bndB, scbB, sBL) CTC_STEP( 5, bndB, scbB, sBL)
        CTC_STEP( 6, bndB, scbB, sBL) CTC_STEP( 7, bndB, scbB, sBL)
        CTC_STEP( 8, bndB, scbB, sBL) CTC_STEP( 9, bndB, scbB, sBL)
        CTC_STEP(10, bndB, scbB, sBL) CTC_STEP(11, bndB, scbB, sBL)
        CTC_STEP(12, bndB, scbB, sBL) CTC_STEP(13, bndB, scbB, sBL)
        CTC_STEP(14, bndB, scbB, sBL)
        STORE_BLK(127)
        asm volatile("" ::: "memory");
        if (lane == 0) *mflag = 128;
    }
#undef CTC_STEP
#undef RUN_BLOCK
#undef LOAD_BLK
#undef LOAD_SCB
#undef UNPACK16
#undef STORE_BLK
#undef PREF_SC
#undef PREF_SC_CLAMP
#undef KA

    // loss: states 399 (wave3 lane7 al1) and 400 (wave3 lane8 al0)
    const float A = __shfl(al1, 7, 64);
    const float B = __shfl(al0, 8, 64);
    if (wid == 3 && lane == 0) {
        const float m  = fmaxf(A, B);
        const float ls = m + __builtin_amdgcn_logf(
            __builtin_amdgcn_exp2f(A - m) + __builtin_amdgcn_exp2f(B - m));
        loss_ws[n] = -ls * K_LN2;   // back to natural log
    }
}

__global__ void ctc_reduce(const float* __restrict__ ws, float* __restrict__ out)
{
    const int tid = threadIdx.x;   // 256 threads, 4 waves
    float v = ws[tid];
    v += __shfl_down(v, 32);
    v += __shfl_down(v, 16);
    v += __shfl_down(v, 8);
    v += __shfl_down(v, 4);
    v += __shfl_down(v, 2);
    v += __shfl_down(v, 1);
    __shared__ float p[4];
    if ((tid & 63) == 0) p[tid >> 6] = v;
    __syncthreads();
    if (tid == 0) out[0] = (p[0] + p[1]) + (p[2] + p[3]);
}

extern "C" void kernel_launch(void* const* d_in, const int* in_sizes, int n_in,
                              void* d_out, int out_size, void* d_ws, size_t ws_size,
                              hipStream_t stream)
{
    const float* pred   = (const float*)d_in[0];
    const int*   target = (const int*)d_in[1];
    // d_in[2] = input_length: unused by the reference computation
    const int*   tlen   = (const int*)d_in[3];
    float* ws = (float*)d_ws;

    ctc_alpha<<<NN, 256, 0, stream>>>(pred, target, tlen, ws);
    ctc_reduce<<<1, NN, 0, stream>>>(ws, (float*)d_out);
}

// Round 19
// 143.015 us; speedup vs baseline: 1.0294x; 1.0294x over previous
//
#include <hip/hip_runtime.h>

// CTC loss forward (sum), faithful to the JAX reference.
// T=2048, N=256, C=128, L=200, S=2L+1=401.
//
// FINAL (r17, best measured 143.4us): one workgroup (4 waves) per sample,
// LOG2 domain, wave w owns states 128w..128w+127, 2/lane (s0=2idx blank,
// s1=2idx+1 label). Intra-wave halo via DPP wave_shr:1 (old operand injects
// the cross-wave boundary). Cross-wave left->right only, 16-step blocks,
// monotonic per-wave flags, double-buffered boundary prefetch, batched
// lane-63 boundary bursts. Wave 0 never waits.
// Emission scores: BLOCK-GRANULAR DOUBLE-BUFFERED REGISTERS filled by
// hand-issued inline-asm global_load_dword ("=&v" early-clobber), one
// counted s_waitcnt vmcnt(32) per block (never 0 in-loop), sched_barrier(0)
// + zero-cost KEEP-ALIVE dataflow fence so neither scheduler hoisting nor
// RA live-range copies can observe a score register before data lands.
// (r18's blank-timeline-in-LDS variant regressed: scattered staging loads
// added +33MB HBM fetch; reverted.)

#define TT 2048
#define NN 256
#define CC 128
#define LL 200

#define K_LOG2E 1.4426950408889634f
#define K_LN2   0.6931471805599453f
#define NEGB   (-1.44e30f)   /* -1e30 * log2(e) */
#define PEN    (-2.0e30f)    /* 'disallowed' halo for wave 0 */
#define NC4    131072u       /* NN*CC*4 bytes: stride between time rows */

__device__ __forceinline__ float max3f(float a, float b, float c) {
    float r; asm("v_max3_f32 %0, %1, %2, %3" : "=v"(r) : "v"(a), "v"(b), "v"(c)); return r;
}

__global__ __launch_bounds__(256, 1)
void ctc_alpha(const float* __restrict__ pred,
               const int* __restrict__ target,
               const int* __restrict__ tlen,
               float* __restrict__ loss_ws)
{
    // [w][b][k]: boundary state 128w+127 AFTER step 16b+1+k; row 4 = PEN.
    __shared__ float blk[5][128][16];
    __shared__ int   flags[8];     // [w]=blocks completed; [7]=INT_MAX dummy

    const int tid  = threadIdx.x;
    const int wid  = tid >> 6;
    const int lane = tid & 63;
    const int n    = blockIdx.x;

    if (tid < 8) flags[tid] = (tid >= 4) ? 0x7fffffff : 0;
    for (int i = tid; i < 128 * 16; i += 256) ((float*)blk[4])[i] = PEN;

    // per-state constants. Reference quirk: starts[0]=0, starts[n>0]=tlen[n-1].
    const int start = (n == 0) ? 0 : tlen[n - 1];
    const int idx   = (wid << 6) | lane;     // s0 = 2*idx (blank), s1 = 2*idx+1
    int lab1 = 0; float msk1 = 0.0f;
    if (idx < LL) {
        lab1 = target[start + idx];
        if (idx >= 1 && lab1 != target[start + idx - 1]) msk1 = 1.0f;
    }

    // ---- alpha_0 (log2 domain): only states 0,1 (idx==0) live ----
    float al0, al1;
    {
        const float eB = pred[n * CC];
        const float eL = pred[n * CC + lab1];
        al0 = (idx == 0) ? K_LOG2E * eB : NEGB;
        al1 = (idx == 0) ? K_LOG2E * eL : NEGB;
    }
    __syncthreads();   // flags + PEN row visible before any spin

    // ---- emission double-buffer: per-lane byte offsets + uniform row ptr ----
    const char* rp = (const char*)pred + (size_t)(NN * CC + n * CC) * 4u;  // row 1
    uint32_t vB = 0u;                         // blank class byte-offset
    uint32_t vL = (uint32_t)lab1 * 4u;        // label class byte-offset
    asm volatile("" : "+v"(vB), "+v"(vL));    // pin to VGPRs

    float sAB[16], sAL[16], sBB[16], sBL[16];   // two 32-reg score sets

    // 32 hand-issued loads for the 16 rows starting at rp (advances rp).
#define PREF_SC(PB, PL)                                                        \
    {                                                                          \
        _Pragma("unroll")                                                      \
        for (int j = 0; j < 16; ++j) {                                         \
            asm volatile("global_load_dword %0, %1, %2"                        \
                : "=&v"(PB[j]) : "v"(vB), "s"(rp) : "memory");                 \
            asm volatile("global_load_dword %0, %1, %2"                        \
                : "=&v"(PL[j]) : "v"(vL), "s"(rp) : "memory");                 \
            rp += NC4;                                                         \
        }                                                                      \
    }
    // Clamped variant for the last prefetch (row 2048 doesn't exist: dup 2047).
#define PREF_SC_CLAMP(PB, PL)                                                  \
    {                                                                          \
        _Pragma("unroll")                                                      \
        for (int j = 0; j < 15; ++j) {                                         \
            asm volatile("global_load_dword %0, %1, %2"                        \
                : "=&v"(PB[j]) : "v"(vB), "s"(rp) : "memory");                 \
            asm volatile("global_load_dword %0, %1, %2"                        \
                : "=&v"(PL[j]) : "v"(vL), "s"(rp) : "memory");                 \
            rp += NC4;                                                         \
        }                                                                      \
        const char* rp2 = rp - NC4;                                            \
        asm volatile("global_load_dword %0, %1, %2"                            \
            : "=&v"(PB[15]) : "v"(vB), "s"(rp2) : "memory");                   \
        asm volatile("global_load_dword %0, %1, %2"                            \
            : "=&v"(PL[15]) : "v"(vL), "s"(rp2) : "memory");                   \
    }

    // Zero-cost dataflow fence: redefine all 16 regs at this program point.
#define KA(S)                                                                  \
    asm volatile("" : "+v"(S[0]), "+v"(S[1]), "+v"(S[2]),  "+v"(S[3]),         \
                      "+v"(S[4]), "+v"(S[5]), "+v"(S[6]),  "+v"(S[7]));        \
    asm volatile("" : "+v"(S[8]), "+v"(S[9]), "+v"(S[10]), "+v"(S[11]),        \
                      "+v"(S[12]),"+v"(S[13]),"+v"(S[14]), "+v"(S[15]));

    asm volatile("s_waitcnt vmcnt(0)" ::: "memory");   // exact vmcnt bookkeeping
    PREF_SC(sAB, sAL)                                  // rows 1..16 -> set A

    float (* const blkC)[16] = blk[(wid == 0) ? 4 : (wid - 1)];
    float (* const blkW)[16] = blk[wid];
    volatile int* pflag = &flags[(wid == 0) ? 7 : (wid - 1)];
    volatile int* mflag = &flags[wid];
    int fval = *pflag;

    float bndA[16], bndB[16], bw[16];
    float bprev = (wid == 0) ? PEN : NEGB;    // boundary after step 0 (alpha0)

#define LOAD_BLK(DST, B)                                                       \
    {                                                                          \
        const float4* q = (const float4*)&blkC[B][0];                          \
        const float4 v0 = q[0], v1 = q[1], v2 = q[2], v3 = q[3];               \
        DST[0]=v0.x;  DST[1]=v0.y;  DST[2]=v0.z;  DST[3]=v0.w;                 \
        DST[4]=v1.x;  DST[5]=v1.y;  DST[6]=v1.z;  DST[7]=v1.w;                 \
        DST[8]=v2.x;  DST[9]=v2.y;  DST[10]=v2.z; DST[11]=v2.w;                \
        DST[12]=v3.x; DST[13]=v3.y; DST[14]=v3.z; DST[15]=v3.w;                \
    }

#define STORE_BLK(B)                                                           \
    if (lane == 63) {                                                          \
        float4* d = (float4*)&blkW[B][0];                                      \
        d[0] = make_float4(bw[0],  bw[1],  bw[2],  bw[3]);                     \
        d[1] = make_float4(bw[4],  bw[5],  bw[6],  bw[7]);                     \
        d[2] = make_float4(bw[8],  bw[9],  bw[10], bw[11]);                    \
        d[3] = make_float4(bw[12], bw[13], bw[14], bw[15]);                    \
    }

    // One step, PH = 0..15 (no loads inside). Halo h1 = prev lane's al1;
    // lane0 <- boundary via update_dpp old operand (wave_shr:1 = 0x138).
#define CTC_STEP(PH, BV, UB, UL)                                               \
    {                                                                          \
        const float hold = ((PH) == 0) ? bprev : BV[((PH) + 15) & 15];         \
        const int h1i = __builtin_amdgcn_update_dpp(                           \
            __float_as_int(hold), __float_as_int(al1), 0x138, 0xf, 0xf, false);\
        const float h1 = __int_as_float(h1i);                                  \
        const float M  = max3f(al1, al0, h1);                                  \
        const float b1 = fmaf(K_LOG2E, UL[PH], M);                             \
        const float b0 = fmaf(K_LOG2E, UB[PH], M);                             \
        const float e1 = __builtin_amdgcn_exp2f(al1 - M);                      \
        const float e0 = __builtin_amdgcn_exp2f(al0 - M);                      \
        const float eh = __builtin_amdgcn_exp2f(h1 - M);                       \
        const float s1 = fmaf(eh, msk1, e1 + e0);                              \
        const float s0 = e0 + eh;                                              \
        al1 = b1 + __builtin_amdgcn_logf(s1);                                  \
        al0 = b0 + __builtin_amdgcn_logf(s0);                                  \
        bw[PH] = al1;                                                          \
    }

    // Block B: consume score set U*, prefetch set P* (rows of block B+1);
    // consume boundaries BUSE, prefetch BPRE (block B+1).
#define RUN_BLOCK(B, UB, UL, PB, PL, BUSE, BPRE, NEED, CLAMP)                  \
    {                                                                          \
        if (CLAMP) { PREF_SC_CLAMP(PB, PL) } else { PREF_SC(PB, PL) }          \
        const int need_ = (NEED);                                              \
        if (fval < need_) { do { fval = *pflag; } while (fval < need_); }      \
        asm volatile("" ::: "memory");                                         \
        LOAD_BLK(BPRE, (B) + 1)                                                \
        asm volatile("s_waitcnt vmcnt(32)" ::: "memory");  /* set U landed */  \
        __builtin_amdgcn_sched_barrier(0);                                     \
        KA(UB) KA(UL)                         /* dataflow fence on set U */    \
        CTC_STEP( 0, BUSE, UB, UL) CTC_STEP( 1, BUSE, UB, UL)                  \
        CTC_STEP( 2, BUSE, UB, UL) CTC_STEP( 3, BUSE, UB, UL)                  \
        CTC_STEP( 4, BUSE, UB, UL) CTC_STEP( 5, BUSE, UB, UL)                  \
        CTC_STEP( 6, BUSE, UB, UL) CTC_STEP( 7, BUSE, UB, UL)                  \
        CTC_STEP( 8, BUSE, UB, UL) CTC_STEP( 9, BUSE, UB, UL)                  \
        CTC_STEP(10, BUSE, UB, UL) CTC_STEP(11, BUSE, UB, UL)                  \
        CTC_STEP(12, BUSE, UB, UL) CTC_STEP(13, BUSE, UB, UL)                  \
        CTC_STEP(14, BUSE, UB, UL) CTC_STEP(15, BUSE, UB, UL)                  \
        STORE_BLK(B)                                                           \
        asm volatile("" ::: "memory");       /* burst before flag post */      \
        if (lane == 0) *mflag = (B) + 1;                                       \
        bprev = BUSE[15];                                                      \
        fval = *pflag;                                                         \
    }

    // prologue: block 0's boundaries (written by producer's block 0)
    if (fval < 1) { do { fval = *pflag; } while (fval < 1); }
    asm volatile("" ::: "memory");
    LOAD_BLK(bndA, 0)

    // main: blocks 0..125 (t = 1..2016), ping-pong score/bnd buffers
    for (int bb = 0; bb < 63; ++bb) {
        RUN_BLOCK(2 * bb,     sAB, sAL, sBB, sBL, bndA, bndB, 2 * bb + 2, 0)
        RUN_BLOCK(2 * bb + 1, sBB, sBL, sAB, sAL, bndB, bndA, 2 * bb + 3, 0)
    }

    // block 126 (t=2017..2032): prefetch rows 2033..2047 (clamped) + bnd 127
    RUN_BLOCK(126, sAB, sAL, sBB, sBL, bndA, bndB, 128, 1)

    // tail block 127: t = 2033..2047 (15 steps), set B + bndB already here.
    {
        asm volatile("s_waitcnt vmcnt(0)" ::: "memory");
        __builtin_amdgcn_sched_barrier(0);
        KA(sBB) KA(sBL)
        CTC_STEP( 0, bndB, sBB, sBL) CTC_STEP( 1, bndB, sBB, sBL)
        CTC_STEP( 2, bndB, sBB, sBL) CTC_STEP( 3, bndB, sBB, sBL)
        CTC_STEP( 4, bndB, sBB, sBL) CTC_STEP( 5, bndB, sBB, sBL)
        CTC_STEP( 6, bndB, sBB, sBL) CTC_STEP( 7, bndB, sBB, sBL)
        CTC_STEP( 8, bndB, sBB, sBL) CTC_STEP( 9, bndB, sBB, sBL)
        CTC_STEP(10, bndB, sBB, sBL) CTC_STEP(11, bndB, sBB, sBL)
        CTC_STEP(12, bndB, sBB, sBL) CTC_STEP(13, bndB, sBB, sBL)
        CTC_STEP(14, bndB, sBB, sBL)
        STORE_BLK(127)
        asm volatile("" ::: "memory");
        if (lane == 0) *mflag = 128;
    }
#undef CTC_STEP
#undef RUN_BLOCK
#undef LOAD_BLK
#undef STORE_BLK
#undef PREF_SC
#undef PREF_SC_CLAMP
#undef KA

    // loss: states 399 (wave3 lane7 al1) and 400 (wave3 lane8 al0)
    const float A = __shfl(al1, 7, 64);
    const float B = __shfl(al0, 8, 64);
    if (wid == 3 && lane == 0) {
        const float m  = fmaxf(A, B);
        const float ls = m + __builtin_amdgcn_logf(
            __builtin_amdgcn_exp2f(A - m) + __builtin_amdgcn_exp2f(B - m));
        loss_ws[n] = -ls * K_LN2;   // back to natural log
    }
}

__global__ void ctc_reduce(const float* __restrict__ ws, float* __restrict__ out)
{
    const int tid = threadIdx.x;   // 256 threads, 4 waves
    float v = ws[tid];
    v += __shfl_down(v, 32);
    v += __shfl_down(v, 16);
    v += __shfl_down(v, 8);
    v += __shfl_down(v, 4);
    v += __shfl_down(v, 2);
    v += __shfl_down(v, 1);
    __shared__ float p[4];
    if ((tid & 63) == 0) p[tid >> 6] = v;
    __syncthreads();
    if (tid == 0) out[0] = (p[0] + p[1]) + (p[2] + p[3]);
}

extern "C" void kernel_launch(void* const* d_in, const int* in_sizes, int n_in,
                              void* d_out, int out_size, void* d_ws, size_t ws_size,
                              hipStream_t stream)
{
    const float* pred   = (const float*)d_in[0];
    const int*   target = (const int*)d_in[1];
    // d_in[2] = input_length: unused by the reference computation
    const int*   tlen   = (const int*)d_in[3];
    float* ws = (float*)d_ws;

    ctc_alpha<<<NN, 256, 0, stream>>>(pred, target, tlen, ws);
    ctc_reduce<<<1, NN, 0, stream>>>(ws, (float*)d_out);
}